// Round 1
// baseline (197.522 us; speedup 1.0000x reference)
//
#include <hip/hip_runtime.h>

// Problem constants (fixed by setup_inputs): mask [64,480,864] fp32.
constexpr int B = 64;
constexpr int H = 480;
constexpr int W = 864;
constexpr float PROB_THRESHOLD = 0.5f;

constexpr int BPS = 16;                        // blocks per sample
constexpr int ROWS_PER_BLK = H / BPS;          // 30
constexpr int W4 = W / 4;                      // 216 float4 per row
constexpr int N4_PER_BLK = ROWS_PER_BLK * W4;  // 6480 float4 per block
constexpr int NBLK = B * BPS;                  // 1024 blocks

// ---------------------------------------------------------------------------
// Kernel 1: per-block partial reduction of (min_r, max_r, min_c, max_c, cnt).
// Each block covers ROWS_PER_BLK contiguous rows of one sample; float4 loads.
// Partials go to part[blockIdx.x*5 .. +4]; no atomics, no init pass needed.
// ---------------------------------------------------------------------------
__global__ __launch_bounds__(256) void reduce_kernel(
    const float* __restrict__ mask, int* __restrict__ part) {
  const int b   = blockIdx.x / BPS;
  const int blk = blockIdx.x % BPS;
  const int row0 = blk * ROWS_PER_BLK;
  const float4* base =
      (const float4*)(mask + (size_t)b * H * W + (size_t)row0 * W);

  int minr = H, maxr = -1, minc = W, maxc = -1, cnt = 0;

  for (int i = threadIdx.x; i < N4_PER_BLK; i += blockDim.x) {
    float4 v = base[i];
    int r = i / W4;                 // const divide -> magic mul
    int c = (i - r * W4) * 4;
    bool h0 = v.x > PROB_THRESHOLD;
    bool h1 = v.y > PROB_THRESHOLD;
    bool h2 = v.z > PROB_THRESHOLD;
    bool h3 = v.w > PROB_THRESHOLD;
    int m = (h0 ? 1 : 0) | (h1 ? 2 : 0) | (h2 ? 4 : 0) | (h3 ? 8 : 0);
    if (m) {
      int rr = row0 + r;
      minr = min(minr, rr);
      maxr = max(maxr, rr);
      int lo = h0 ? c : (h1 ? c + 1 : (h2 ? c + 2 : c + 3));
      int hi = h3 ? c + 3 : (h2 ? c + 2 : (h1 ? c + 1 : c));
      minc = min(minc, lo);
      maxc = max(maxc, hi);
      cnt += __popc(m);
    }
  }

  // Wave (64-lane) shuffle reduction.
  for (int off = 32; off > 0; off >>= 1) {
    minr = min(minr, __shfl_down(minr, off));
    maxr = max(maxr, __shfl_down(maxr, off));
    minc = min(minc, __shfl_down(minc, off));
    maxc = max(maxc, __shfl_down(maxc, off));
    cnt += __shfl_down(cnt, off);
  }

  // Cross-wave (4 waves @ 256 threads) via LDS.
  __shared__ int s[4][5];
  const int wave = threadIdx.x >> 6;
  if ((threadIdx.x & 63) == 0) {
    s[wave][0] = minr; s[wave][1] = maxr;
    s[wave][2] = minc; s[wave][3] = maxc;
    s[wave][4] = cnt;
  }
  __syncthreads();
  if (threadIdx.x == 0) {
    for (int wv = 1; wv < 4; ++wv) {
      minr = min(minr, s[wv][0]);
      maxr = max(maxr, s[wv][1]);
      minc = min(minc, s[wv][2]);
      maxc = max(maxc, s[wv][3]);
      cnt += s[wv][4];
    }
    int* p = part + (size_t)blockIdx.x * 5;
    p[0] = minr; p[1] = maxr; p[2] = minc; p[3] = maxc; p[4] = cnt;
  }
}

// ---------------------------------------------------------------------------
// Kernel 2: fold BPS partials per sample, apply the full-frame rule + loosen
// + clip, emit bbox to d_out tail (as float32, since the flat output buffer
// is read back as fp32) and to workspace (as int) for the fill kernel.
// One block of B threads.
// ---------------------------------------------------------------------------
__global__ __launch_bounds__(64) void finalize_kernel(
    const int* __restrict__ part, const int* __restrict__ n_pts_threshold,
    const int* __restrict__ n_bbox_loose, float* __restrict__ bbox_out,
    int* __restrict__ bbox_ws) {
  const int b = threadIdx.x;
  int minr = H, maxr = -1, minc = W, maxc = -1, cnt = 0;
  for (int k = 0; k < BPS; ++k) {
    const int* p = part + (size_t)(b * BPS + k) * 5;
    minr = min(minr, p[0]);
    maxr = max(maxr, p[1]);
    minc = min(minc, p[2]);
    maxc = max(maxc, p[3]);
    cnt += p[4];
  }
  const int thr = n_pts_threshold[0];
  const int loose = n_bbox_loose[0];
  int y0, y1, x0, x1;
  if (cnt < thr) {
    y0 = 0; y1 = H - 1; x0 = 0; x1 = W - 1;
  } else {
    y0 = min(max(minr - loose, 0), H - 1);
    y1 = min(max(maxr + loose, 0), H - 1);
    x0 = min(max(minc - loose, 0), W - 1);
    x1 = min(max(maxc + loose, 0), W - 1);
  }
  bbox_out[b * 4 + 0] = (float)y0;
  bbox_out[b * 4 + 1] = (float)y1;
  bbox_out[b * 4 + 2] = (float)x0;
  bbox_out[b * 4 + 3] = (float)x1;
  bbox_ws[b * 4 + 0] = y0;
  bbox_ws[b * 4 + 1] = y1;
  bbox_ws[b * 4 + 2] = x0;
  bbox_ws[b * 4 + 3] = x1;
}

// ---------------------------------------------------------------------------
// Kernel 3: write att_map as 0/1 per the per-sample bbox. float4 stores.
// ---------------------------------------------------------------------------
__global__ __launch_bounds__(256) void fill_kernel(
    const int* __restrict__ bbox_ws, float* __restrict__ out) {
  const int b   = blockIdx.x / BPS;
  const int blk = blockIdx.x % BPS;
  const int row0 = blk * ROWS_PER_BLK;
  const int y0 = bbox_ws[b * 4 + 0];
  const int y1 = bbox_ws[b * 4 + 1];
  const int x0 = bbox_ws[b * 4 + 2];
  const int x1 = bbox_ws[b * 4 + 3];
  float4* base = (float4*)(out + (size_t)b * H * W + (size_t)row0 * W);

  for (int i = threadIdx.x; i < N4_PER_BLK; i += blockDim.x) {
    int r = i / W4;
    int c = (i - r * W4) * 4;
    int rr = row0 + r;
    bool inr = (rr >= y0) & (rr <= y1);
    float4 v;
    v.x = (inr & (c + 0 >= x0) & (c + 0 <= x1)) ? 1.0f : 0.0f;
    v.y = (inr & (c + 1 >= x0) & (c + 1 <= x1)) ? 1.0f : 0.0f;
    v.z = (inr & (c + 2 >= x0) & (c + 2 <= x1)) ? 1.0f : 0.0f;
    v.w = (inr & (c + 3 >= x0) & (c + 3 <= x1)) ? 1.0f : 0.0f;
    base[i] = v;
  }
}

extern "C" void kernel_launch(void* const* d_in, const int* in_sizes, int n_in,
                              void* d_out, int out_size, void* d_ws,
                              size_t ws_size, hipStream_t stream) {
  const float* mask = (const float*)d_in[0];
  const int* n_pts_threshold = (const int*)d_in[1];
  const int* n_bbox_loose = (const int*)d_in[2];

  float* out = (float*)d_out;
  float* bbox_out = out + (size_t)B * H * W;  // tuple outputs concatenated

  int* part = (int*)d_ws;             // NBLK * 5 ints
  int* bbox_ws = part + NBLK * 5;     // B * 4 ints

  reduce_kernel<<<NBLK, 256, 0, stream>>>(mask, part);
  finalize_kernel<<<1, B, 0, stream>>>(part, n_pts_threshold, n_bbox_loose,
                                       bbox_out, bbox_ws);
  fill_kernel<<<NBLK, 256, 0, stream>>>(bbox_ws, out);
}

// Round 2
// 194.186 us; speedup vs baseline: 1.0172x; 1.0172x over previous
//
#include <hip/hip_runtime.h>

// Problem constants (fixed by setup_inputs): mask [64,480,864] fp32.
constexpr int B = 64;
constexpr int H = 480;
constexpr int W = 864;
constexpr float PROB_THRESHOLD = 0.5f;

constexpr int BPS = 16;                        // blocks per sample (power of 2)
constexpr int ROWS_PER_BLK = H / BPS;          // 30
constexpr int W4 = W / 4;                      // 216 float4 per row
constexpr int N4_PER_BLK = ROWS_PER_BLK * W4;  // 6480 float4 per block
constexpr int NBLK = B * BPS;                  // 1024 blocks

// ---------------------------------------------------------------------------
// Kernel 1: per-block partial reduction of (min_r, max_r, min_c, max_c, cnt).
// Each block covers ROWS_PER_BLK contiguous rows of one sample.
// 4x-unrolled independent float4 loads for memory-level parallelism.
// Partials -> part[blockIdx.x*5 .. +4]. No atomics, no init pass.
// ---------------------------------------------------------------------------
__global__ __launch_bounds__(256) void reduce_kernel(
    const float* __restrict__ mask, int* __restrict__ part) {
  const int b   = blockIdx.x >> 4;   // / BPS
  const int blk = blockIdx.x & 15;   // % BPS
  const int row0 = blk * ROWS_PER_BLK;
  const float4* base =
      (const float4*)(mask + ((size_t)b * H + row0) * (size_t)W);

  int minr = H, maxr = -1, minc = W, maxc = -1, cnt = 0;

  auto process = [&](float4 v, int i) {
    int r = i / W4;                 // const divide -> magic mul
    int c = (i - r * W4) * 4;
    bool h0 = v.x > PROB_THRESHOLD;
    bool h1 = v.y > PROB_THRESHOLD;
    bool h2 = v.z > PROB_THRESHOLD;
    bool h3 = v.w > PROB_THRESHOLD;
    int m = (h0 ? 1 : 0) | (h1 ? 2 : 0) | (h2 ? 4 : 0) | (h3 ? 8 : 0);
    if (m) {
      int rr = row0 + r;
      minr = min(minr, rr);
      maxr = max(maxr, rr);
      int lo = c + (h0 ? 0 : (h1 ? 1 : (h2 ? 2 : 3)));
      int hi = c + (h3 ? 3 : (h2 ? 2 : (h1 ? 1 : 0)));
      minc = min(minc, lo);
      maxc = max(maxc, hi);
      cnt += __popc(m);
    }
  };

  // 6480 = 6*1024 + 256 + 80. Main loop: 4 independent loads in flight.
  int i = threadIdx.x;
  for (int it = 0; it < 6; ++it, i += 1024) {
    float4 v0 = base[i];
    float4 v1 = base[i + 256];
    float4 v2 = base[i + 512];
    float4 v3 = base[i + 768];
    process(v0, i);
    process(v1, i + 256);
    process(v2, i + 512);
    process(v3, i + 768);
  }
  // i = tid + 6144: all 256 threads valid (6144..6399 < 6480)
  process(base[i], i);
  i += 256;                          // 6400..6655: only tid < 80 valid
  if (i < N4_PER_BLK) process(base[i], i);

  // Wave (64-lane) shuffle reduction.
  for (int off = 32; off > 0; off >>= 1) {
    minr = min(minr, __shfl_down(minr, off));
    maxr = max(maxr, __shfl_down(maxr, off));
    minc = min(minc, __shfl_down(minc, off));
    maxc = max(maxc, __shfl_down(maxc, off));
    cnt += __shfl_down(cnt, off);
  }

  // Cross-wave (4 waves @ 256 threads) via LDS.
  __shared__ int s[4][5];
  const int wave = threadIdx.x >> 6;
  if ((threadIdx.x & 63) == 0) {
    s[wave][0] = minr; s[wave][1] = maxr;
    s[wave][2] = minc; s[wave][3] = maxc;
    s[wave][4] = cnt;
  }
  __syncthreads();
  if (threadIdx.x == 0) {
    for (int wv = 1; wv < 4; ++wv) {
      minr = min(minr, s[wv][0]);
      maxr = max(maxr, s[wv][1]);
      minc = min(minc, s[wv][2]);
      maxc = max(maxc, s[wv][3]);
      cnt += s[wv][4];
    }
    int* p = part + (size_t)blockIdx.x * 5;
    p[0] = minr; p[1] = maxr; p[2] = minc; p[3] = maxc; p[4] = cnt;
  }
}

// ---------------------------------------------------------------------------
// Kernel 2: every block re-folds its sample's 16 partials (80 ints, L2-hot,
// uniform address -> broadcast), applies full-frame rule + loosen + clip,
// then writes its slice of att_map with float4 stores. The blk==0 block's
// thread 0 also writes the bbox floats to the d_out tail.
// Folding in-block removes the separate finalize launch.
// ---------------------------------------------------------------------------
__global__ __launch_bounds__(256) void fill_kernel(
    const int* __restrict__ part, const int* __restrict__ n_pts_threshold,
    const int* __restrict__ n_bbox_loose, float* __restrict__ out,
    float* __restrict__ bbox_out) {
  const int b   = blockIdx.x >> 4;
  const int blk = blockIdx.x & 15;
  const int row0 = blk * ROWS_PER_BLK;

  int minr = H, maxr = -1, minc = W, maxc = -1, cnt = 0;
  const int* p = part + (size_t)b * BPS * 5;
#pragma unroll
  for (int k = 0; k < BPS; ++k) {
    minr = min(minr, p[k * 5 + 0]);
    maxr = max(maxr, p[k * 5 + 1]);
    minc = min(minc, p[k * 5 + 2]);
    maxc = max(maxc, p[k * 5 + 3]);
    cnt += p[k * 5 + 4];
  }
  const int thr   = n_pts_threshold[0];
  const int loose = n_bbox_loose[0];
  int y0, y1, x0, x1;
  if (cnt < thr) {
    y0 = 0; y1 = H - 1; x0 = 0; x1 = W - 1;
  } else {
    y0 = min(max(minr - loose, 0), H - 1);
    y1 = min(max(maxr + loose, 0), H - 1);
    x0 = min(max(minc - loose, 0), W - 1);
    x1 = min(max(maxc + loose, 0), W - 1);
  }
  if (blk == 0 && threadIdx.x == 0) {
    bbox_out[b * 4 + 0] = (float)y0;
    bbox_out[b * 4 + 1] = (float)y1;
    bbox_out[b * 4 + 2] = (float)x0;
    bbox_out[b * 4 + 3] = (float)x1;
  }

  float4* base = (float4*)(out + ((size_t)b * H + row0) * (size_t)W);

  auto val4 = [&](int i) {
    int r = i / W4;
    int c = (i - r * W4) * 4;
    int rr = row0 + r;
    bool inr = (rr >= y0) & (rr <= y1);
    float4 v;
    v.x = (inr & (c + 0 >= x0) & (c + 0 <= x1)) ? 1.0f : 0.0f;
    v.y = (inr & (c + 1 >= x0) & (c + 1 <= x1)) ? 1.0f : 0.0f;
    v.z = (inr & (c + 2 >= x0) & (c + 2 <= x1)) ? 1.0f : 0.0f;
    v.w = (inr & (c + 3 >= x0) & (c + 3 <= x1)) ? 1.0f : 0.0f;
    return v;
  };

  int i = threadIdx.x;
  for (int it = 0; it < 6; ++it, i += 1024) {
    base[i]       = val4(i);
    base[i + 256] = val4(i + 256);
    base[i + 512] = val4(i + 512);
    base[i + 768] = val4(i + 768);
  }
  base[i] = val4(i);
  i += 256;
  if (i < N4_PER_BLK) base[i] = val4(i);
}

extern "C" void kernel_launch(void* const* d_in, const int* in_sizes, int n_in,
                              void* d_out, int out_size, void* d_ws,
                              size_t ws_size, hipStream_t stream) {
  const float* mask = (const float*)d_in[0];
  const int* n_pts_threshold = (const int*)d_in[1];
  const int* n_bbox_loose = (const int*)d_in[2];

  float* out = (float*)d_out;
  float* bbox_out = out + (size_t)B * H * W;  // tuple outputs concatenated

  int* part = (int*)d_ws;  // NBLK * 5 ints

  reduce_kernel<<<NBLK, 256, 0, stream>>>(mask, part);
  fill_kernel<<<NBLK, 256, 0, stream>>>(part, n_pts_threshold, n_bbox_loose,
                                        out, bbox_out);
}

// Round 4
// 183.124 us; speedup vs baseline: 1.0786x; 1.0604x over previous
//
#include <hip/hip_runtime.h>

// Problem constants (fixed by setup_inputs): mask [64,480,864] fp32.
constexpr int B = 64;
constexpr int H = 480;
constexpr int W = 864;
constexpr float PROB_THRESHOLD = 0.5f;

constexpr int BPS = 16;                        // blocks per sample (power of 2)
constexpr int ROWS_PER_BLK = H / BPS;          // 30
constexpr int W4 = W / 4;                      // 216 float4 per row
constexpr int N4_PER_BLK = ROWS_PER_BLK * W4;  // 6480 float4 per block
constexpr int NBLK = B * BPS;                  // 1024 blocks

using f32x4 = __attribute__((ext_vector_type(4))) float;

// ---------------------------------------------------------------------------
// Kernel 1: per-block partial (min_r, max_r, min_c, max_c, cnt) over 30 rows
// of one sample. 8-deep independent non-temporal float4 loads for MLP.
// Partials -> part[blockIdx.x*5 .. +4]. No atomics, no init pass.
// ---------------------------------------------------------------------------
__global__ __launch_bounds__(256) void reduce_kernel(
    const float* __restrict__ mask, int* __restrict__ part) {
  const int b    = blockIdx.x >> 4;  // / BPS
  const int blk  = blockIdx.x & 15;  // % BPS
  const int row0 = blk * ROWS_PER_BLK;
  const f32x4* __restrict__ base =
      (const f32x4*)(mask + ((size_t)b * H + row0) * (size_t)W);

  int minr = H, maxr = -1, minc = W, maxc = -1, cnt = 0;

  auto process = [&](f32x4 v, int i) {
    int r = i / W4;                  // const divide -> magic mul
    int c = (i - r * W4) * 4;
    bool h0 = v.x > PROB_THRESHOLD;
    bool h1 = v.y > PROB_THRESHOLD;
    bool h2 = v.z > PROB_THRESHOLD;
    bool h3 = v.w > PROB_THRESHOLD;
    int m = (h0 ? 1 : 0) | (h1 ? 2 : 0) | (h2 ? 4 : 0) | (h3 ? 8 : 0);
    if (m) {
      int rr = row0 + r;
      minr = min(minr, rr);
      maxr = max(maxr, rr);
      int lo = c + (h0 ? 0 : (h1 ? 1 : (h2 ? 2 : 3)));
      int hi = c + (h3 ? 3 : (h2 ? 2 : (h1 ? 1 : 0)));
      minc = min(minc, lo);
      maxc = max(maxc, hi);
      cnt += __popc(m);
    }
  };

  // 6480 = 3*2048 + 256 + 80. Main loop: 8 independent loads in flight.
  int i = threadIdx.x;
  for (int it = 0; it < 3; ++it, i += 2048) {
    f32x4 v[8];
#pragma unroll
    for (int k = 0; k < 8; ++k)
      v[k] = __builtin_nontemporal_load(&base[i + k * 256]);
#pragma unroll
    for (int k = 0; k < 8; ++k) process(v[k], i + k * 256);
  }
  // i = tid + 6144: all 256 threads valid (6144..6399 < 6480)
  process(__builtin_nontemporal_load(&base[i]), i);
  i += 256;  // 6400..6655: only tid < 80 valid
  if (i < N4_PER_BLK) process(__builtin_nontemporal_load(&base[i]), i);

  // Wave (64-lane) shuffle reduction.
  for (int off = 32; off > 0; off >>= 1) {
    minr = min(minr, __shfl_down(minr, off));
    maxr = max(maxr, __shfl_down(maxr, off));
    minc = min(minc, __shfl_down(minc, off));
    maxc = max(maxc, __shfl_down(maxc, off));
    cnt += __shfl_down(cnt, off);
  }

  // Cross-wave (4 waves @ 256 threads) via LDS.
  __shared__ int s[4][5];
  const int wave = threadIdx.x >> 6;
  if ((threadIdx.x & 63) == 0) {
    s[wave][0] = minr; s[wave][1] = maxr;
    s[wave][2] = minc; s[wave][3] = maxc;
    s[wave][4] = cnt;
  }
  __syncthreads();
  if (threadIdx.x == 0) {
    for (int wv = 1; wv < 4; ++wv) {
      minr = min(minr, s[wv][0]);
      maxr = max(maxr, s[wv][1]);
      minc = min(minc, s[wv][2]);
      maxc = max(maxc, s[wv][3]);
      cnt += s[wv][4];
    }
    int* p = part + (size_t)blockIdx.x * 5;
    p[0] = minr; p[1] = maxr; p[2] = minc; p[3] = maxc; p[4] = cnt;
  }
}

// ---------------------------------------------------------------------------
// Kernel 2: every block re-folds its sample's 16 partials (80 L2-hot ints,
// uniform address -> broadcast), applies full-frame rule + loosen + clip,
// then writes its att_map slice with non-temporal float4 stores. The blk==0
// block's thread 0 also writes the bbox floats to the d_out tail.
// ---------------------------------------------------------------------------
__global__ __launch_bounds__(256) void fill_kernel(
    const int* __restrict__ part, const int* __restrict__ n_pts_threshold,
    const int* __restrict__ n_bbox_loose, float* __restrict__ out,
    float* __restrict__ bbox_out) {
  const int b    = blockIdx.x >> 4;
  const int blk  = blockIdx.x & 15;
  const int row0 = blk * ROWS_PER_BLK;

  int minr = H, maxr = -1, minc = W, maxc = -1, cnt = 0;
  const int* p = part + (size_t)b * BPS * 5;
#pragma unroll
  for (int k = 0; k < BPS; ++k) {
    minr = min(minr, p[k * 5 + 0]);
    maxr = max(maxr, p[k * 5 + 1]);
    minc = min(minc, p[k * 5 + 2]);
    maxc = max(maxc, p[k * 5 + 3]);
    cnt += p[k * 5 + 4];
  }
  const int thr   = n_pts_threshold[0];
  const int loose = n_bbox_loose[0];
  int y0, y1, x0, x1;
  if (cnt < thr) {
    y0 = 0; y1 = H - 1; x0 = 0; x1 = W - 1;
  } else {
    y0 = min(max(minr - loose, 0), H - 1);
    y1 = min(max(maxr + loose, 0), H - 1);
    x0 = min(max(minc - loose, 0), W - 1);
    x1 = min(max(maxc + loose, 0), W - 1);
  }
  if (blk == 0 && threadIdx.x == 0) {
    bbox_out[b * 4 + 0] = (float)y0;
    bbox_out[b * 4 + 1] = (float)y1;
    bbox_out[b * 4 + 2] = (float)x0;
    bbox_out[b * 4 + 3] = (float)x1;
  }

  f32x4* obase = (f32x4*)(out + ((size_t)b * H + row0) * (size_t)W);

  auto val4 = [&](int i2) {
    int r = i2 / W4;
    int c = (i2 - r * W4) * 4;
    int rr = row0 + r;
    bool inr = (rr >= y0) & (rr <= y1);
    f32x4 v;
    v.x = (inr & (c + 0 >= x0) & (c + 0 <= x1)) ? 1.0f : 0.0f;
    v.y = (inr & (c + 1 >= x0) & (c + 1 <= x1)) ? 1.0f : 0.0f;
    v.z = (inr & (c + 2 >= x0) & (c + 2 <= x1)) ? 1.0f : 0.0f;
    v.w = (inr & (c + 3 >= x0) & (c + 3 <= x1)) ? 1.0f : 0.0f;
    return v;
  };

  int i = threadIdx.x;
  for (int it = 0; it < 6; ++it, i += 1024) {
    __builtin_nontemporal_store(val4(i),       &obase[i]);
    __builtin_nontemporal_store(val4(i + 256), &obase[i + 256]);
    __builtin_nontemporal_store(val4(i + 512), &obase[i + 512]);
    __builtin_nontemporal_store(val4(i + 768), &obase[i + 768]);
  }
  __builtin_nontemporal_store(val4(i), &obase[i]);
  i += 256;
  if (i < N4_PER_BLK) __builtin_nontemporal_store(val4(i), &obase[i]);
}

extern "C" void kernel_launch(void* const* d_in, const int* in_sizes, int n_in,
                              void* d_out, int out_size, void* d_ws,
                              size_t ws_size, hipStream_t stream) {
  const float* mask = (const float*)d_in[0];
  const int* n_pts_threshold = (const int*)d_in[1];
  const int* n_bbox_loose = (const int*)d_in[2];

  float* out = (float*)d_out;
  float* bbox_out = out + (size_t)B * H * W;  // tuple outputs concatenated
  int* part = (int*)d_ws;                     // NBLK * 5 ints

  reduce_kernel<<<NBLK, 256, 0, stream>>>(mask, part);
  fill_kernel<<<NBLK, 256, 0, stream>>>(part, n_pts_threshold, n_bbox_loose,
                                        out, bbox_out);
}